// Round 8
// baseline (1004.586 us; speedup 1.0000x reference)
//
#include <hip/hip_runtime.h>
#include <math.h>

#define BATCH 256
#define NNODE 128
#define NT    32768      // BATCH*NNODE
#define FDIM  128
#define NEDGE 262144
#define LBL   29
#define MAXDEG 16
#define RWD   16
#define NTF   (NT * FDIM)
#define EMAX  1408       // per-graph edge buffer (mean 1024, sigma ~32; fallback past this)

// ---------------------------------------------------------------- CSR build
__global__ void k_zero_i(int* __restrict__ p, int n) {
  int i = blockIdx.x * 256 + threadIdx.x;
  if (i < n) p[i] = 0;
}
__global__ void k_deg_count(const int* __restrict__ dst, int* __restrict__ degi) {
  int e = blockIdx.x * 256 + threadIdx.x;
  if (e < NEDGE) atomicAdd(&degi[dst[e]], 1);
}
__global__ void k_dinv(const int* __restrict__ degi, float* __restrict__ dinv, int n) {
  int i = blockIdx.x * 256 + threadIdx.x;
  if (i < n) dinv[i] = rsqrtf((float)(degi[i] + 1));   // +1 self loop
}
__global__ __launch_bounds__(1024) void k_scan(const int* __restrict__ degi,
                                               int* __restrict__ ofs,
                                               int* __restrict__ cur) {
  __shared__ int part[1024];
  int t = threadIdx.x;
  int base = t * 32;
  int loc[32]; int sum = 0;
#pragma unroll
  for (int u = 0; u < 32; ++u) { loc[u] = sum; sum += degi[base + u]; }
  part[t] = sum;
  __syncthreads();
  for (int off = 1; off < 1024; off <<= 1) {
    int v = (t >= off) ? part[t - off] : 0;
    __syncthreads();
    part[t] += v;
    __syncthreads();
  }
  int excl = (t == 0) ? 0 : part[t - 1];
#pragma unroll
  for (int u = 0; u < 32; ++u) {
    int o = excl + loc[u];
    ofs[base + u] = o; cur[base + u] = o;
  }
}
__global__ void k_csr_fill(const int* __restrict__ src, const int* __restrict__ dst,
                           int* __restrict__ cur, int* __restrict__ csr) {
  int e = blockIdx.x * 256 + threadIdx.x;
  if (e < NEDGE) {
    int pos = atomicAdd(&cur[dst[e]], 1);
    csr[pos] = src[e];
  }
}

// ---------------------------------------------------------------- fused per-graph chain
// One block = one (graph, side). 512 threads.
// __launch_bounds__(512, 1): empirically the 2nd arg acts like CUDA's
// min-BLOCKS-per-CU on this toolchain (R5/R6/R7 VGPR evidence: (512,2) and
// plain (512) -> cap 128 + GBs of scratch spill; (256) default -> 132 regs,
// no spill). 1 block * 8 waves = 2 waves/EU -> VGPR cap 256, no spill, and
// 2 waves/SIMD overlap LDS latency with VALU.
// LDS mappings: W reads use split columns {jq, 64+jq} -> 16-lane contiguous
// b128, 2 dw/bank (free); gather uses 4 threads/node at cols 4l+16u
// (distinct banks intra-node). R7 measured conflicts 3.0e7 -> 5.6e6.
__global__ __launch_bounds__(512, 1) void k_chain(
    const float* __restrict__ x1, const int* __restrict__ cent1, const float* __restrict__ rw1,
    const float* __restrict__ x2, const int* __restrict__ cent2, const float* __restrict__ rw2,
    const float* __restrict__ demb,
    const float* __restrict__ initW, const float* __restrict__ initb,
    const float* __restrict__ W1, const float* __restrict__ b1,
    const float* __restrict__ W2, const float* __restrict__ b2,
    const float* __restrict__ W3, const float* __restrict__ b3,
    const int* __restrict__ ofs1, const int* __restrict__ end1, const int* __restrict__ csr1,
    const int* __restrict__ ofs2, const int* __restrict__ end2, const int* __restrict__ csr2,
    const float* __restrict__ dinv1, const float* __restrict__ dinv2,
    float* __restrict__ feat1G, float* __restrict__ feat2G,
    float* __restrict__ f13G, float* __restrict__ f23G,
    float* __restrict__ gfs) {
  __shared__ float featL[128 * 132];
  __shared__ float hL[128 * 132];     // phase 0: concat overlay [128*68]
  __shared__ float WcB[32 * 132];     // pool tmp overlay [16*128]
  __shared__ float dvL[128];
  __shared__ float bL[128];
  __shared__ int   oL[128], enL[128];
  __shared__ int   eLbuf[EMAX];

  const int t = threadIdx.x;
  const int side = blockIdx.x >> 8;
  const int g = blockIdx.x & 255;
  const int nb = g * NNODE;

  const float* xg    = side ? x2 : x1;
  const int*   centg = side ? cent2 : cent1;
  const float* rwg   = side ? rw2 : rw1;
  const int*   ofsg  = side ? ofs2 : ofs1;
  const int*   endg  = side ? end2 : end1;
  const int*   csrg  = side ? csr2 : csr1;
  const float* dinvg = side ? dinv2 : dinv1;
  float* featG = side ? feat2G : feat1G;
  float* f3G   = side ? f23G : f13G;

  // -------- phase -1: stage dinv / csr offsets / edge list / concat features
  const int e_base = ofsg[nb];
  const int e_cnt  = endg[nb + NNODE - 1] - e_base;
  if (t < 128) {
    dvL[t] = dinvg[nb + t];
    oL[t]  = ofsg[nb + t] - e_base;
    enL[t] = endg[nb + t] - e_base;
  }
  for (int idx = t; idx < e_cnt; idx += 512)
    if (idx < EMAX) eLbuf[idx] = csrg[e_base + idx] - nb;
  {
    int d = t >> 2, sub = t & 3;          // 4 threads per node, 17 cols each
    int node = nb + d;
    int ct = centg[node];
    const float* xr = xg + (size_t)node * LBL;
    const float* er = demb + ct * MAXDEG;
    const float* rr = rwg + (size_t)node * RWD;
    float* cL = hL;   // concat overlay [128][68]
    for (int c = sub * 17; c < sub * 17 + 17; ++c) {
      float v = 0.f;
      if (c < LBL) v = xr[c];
      else if (c < LBL + MAXDEG) v = er[c - LBL];
      else if (c < 61) v = rr[c - 45];
      cL[d * 68 + c] = v;
    }
  }
  __syncthreads();

  const int i0 = (t >> 4) * 4;     // 0..124  (32 row-groups)
  const int jq = (t & 15) * 4;     // cols jq..jq+3 and 64+jq..64+jq+3

  // -------- phase 0: featL = relu(concat @ initW + initb); write featG; pool layer0
  {
    float acc[4][8] = {};
    const float* cL = hL;
    for (int kc = 0; kc < 64; kc += 32) {
      __syncthreads();
#pragma unroll
      for (int u = 0; u < 2; ++u) {
        int l = t + 512 * u;                  // 0..1023
        int row = l >> 5, c4 = (l & 31) * 4;
        int gk = kc + row;
        float4 w = (gk < 61) ? *reinterpret_cast<const float4*>(&initW[(size_t)gk * FDIM + c4])
                             : make_float4(0.f, 0.f, 0.f, 0.f);
        *reinterpret_cast<float4*>(&WcB[row * 132 + c4]) = w;
      }
      if (kc == 0 && t < 128) bL[t] = initb[t];
      __syncthreads();
      for (int kk = 0; kk < 32; kk += 4) {
        float av[4][4];
#pragma unroll
        for (int r = 0; r < 4; ++r) {
          float4 tmp = *reinterpret_cast<const float4*>(&cL[(i0 + r) * 68 + kc + kk]);
          av[r][0] = tmp.x; av[r][1] = tmp.y; av[r][2] = tmp.z; av[r][3] = tmp.w;
        }
#pragma unroll
        for (int c = 0; c < 4; ++c) {
          float4 w0 = *reinterpret_cast<const float4*>(&WcB[(kk + c) * 132 + jq]);
          float4 w1 = *reinterpret_cast<const float4*>(&WcB[(kk + c) * 132 + 64 + jq]);
#pragma unroll
          for (int r = 0; r < 4; ++r) {
            float a = av[r][c];
            acc[r][0] += a * w0.x; acc[r][1] += a * w0.y; acc[r][2] += a * w0.z; acc[r][3] += a * w0.w;
            acc[r][4] += a * w1.x; acc[r][5] += a * w1.y; acc[r][6] += a * w1.z; acc[r][7] += a * w1.w;
          }
        }
      }
    }
    __syncthreads();
    float4 bl0 = *reinterpret_cast<const float4*>(&bL[jq]);
    float4 bl1 = *reinterpret_cast<const float4*>(&bL[64 + jq]);
#pragma unroll
    for (int r = 0; r < 4; ++r) {
      float4 o0 = make_float4(fmaxf(acc[r][0] + bl0.x, 0.f), fmaxf(acc[r][1] + bl0.y, 0.f),
                              fmaxf(acc[r][2] + bl0.z, 0.f), fmaxf(acc[r][3] + bl0.w, 0.f));
      float4 o1 = make_float4(fmaxf(acc[r][4] + bl1.x, 0.f), fmaxf(acc[r][5] + bl1.y, 0.f),
                              fmaxf(acc[r][6] + bl1.z, 0.f), fmaxf(acc[r][7] + bl1.w, 0.f));
      *reinterpret_cast<float4*>(&featL[(i0 + r) * 132 + jq]) = o0;
      *reinterpret_cast<float4*>(&featL[(i0 + r) * 132 + 64 + jq]) = o1;
      *reinterpret_cast<float4*>(&featG[(size_t)(nb + i0 + r) * FDIM + jq]) = o0;
      *reinterpret_cast<float4*>(&featG[(size_t)(nb + i0 + r) * FDIM + 64 + jq]) = o1;
    }
    __syncthreads();
  }

  // -------- pool helper (512 threads: 16 row-groups x 8 rows)
#define POOL_LAYER(layer)                                                            \
  {                                                                                  \
    int j4 = (t & 31) * 4, qq = t >> 5;                                              \
    float4 pv = side ? make_float4(-INFINITY, -INFINITY, -INFINITY, -INFINITY)       \
                     : make_float4(0.f, 0.f, 0.f, 0.f);                              \
    for (int r = 0; r < 8; ++r) {                                                    \
      float4 fv = *reinterpret_cast<const float4*>(&featL[(qq * 8 + r) * 132 + j4]); \
      if (side) { pv.x = fmaxf(pv.x, fv.x); pv.y = fmaxf(pv.y, fv.y);                \
                  pv.z = fmaxf(pv.z, fv.z); pv.w = fmaxf(pv.w, fv.w); }              \
      else      { pv.x += fv.x; pv.y += fv.y; pv.z += fv.z; pv.w += fv.w; }          \
    }                                                                                \
    *reinterpret_cast<float4*>(&WcB[qq * 128 + j4]) = pv;                            \
    __syncthreads();                                                                 \
    if (t < 128) {                                                                   \
      float v = side ? -INFINITY : 0.f;                                              \
      for (int q2 = 0; q2 < 16; ++q2) {                                              \
        float w2 = WcB[q2 * 128 + t];                                                \
        v = side ? fmaxf(v, w2) : (v + w2);                                          \
      }                                                                              \
      gfs[g * 1024 + side * 512 + (layer) * 128 + t] = v;                            \
    }                                                                                \
  }

  POOL_LAYER(0)

  // -------- 3 conv layers
  for (int l = 0; l < 3; ++l) {
    const float* Wg = (l == 0) ? W1 : (l == 1) ? W2 : W3;   // SGPR select
    const float* bg = (l == 0) ? b1 : (l == 1) ? b2 : b3;
    // mm: hL = (l>0 ? relu(featL) : featL) @ W_l
    float acc[4][8] = {};
    for (int kc = 0; kc < 128; kc += 32) {
      __syncthreads();   // protects WcB (pool tmp / prev chunk)
#pragma unroll
      for (int u = 0; u < 2; ++u) {
        int ll = t + 512 * u;
        int row = ll >> 5, c4 = (ll & 31) * 4;
        *reinterpret_cast<float4*>(&WcB[row * 132 + c4]) =
            *reinterpret_cast<const float4*>(&Wg[(size_t)(kc + row) * FDIM + c4]);
      }
      if (kc == 0 && t < 128) bL[t] = bg[t];
      __syncthreads();
      for (int kk = 0; kk < 32; kk += 4) {
        float av[4][4];
#pragma unroll
        for (int r = 0; r < 4; ++r) {
          float4 tmp = *reinterpret_cast<const float4*>(&featL[(i0 + r) * 132 + kc + kk]);
          if (l > 0) {
            tmp.x = fmaxf(tmp.x, 0.f); tmp.y = fmaxf(tmp.y, 0.f);
            tmp.z = fmaxf(tmp.z, 0.f); tmp.w = fmaxf(tmp.w, 0.f);
          }
          av[r][0] = tmp.x; av[r][1] = tmp.y; av[r][2] = tmp.z; av[r][3] = tmp.w;
        }
#pragma unroll
        for (int c = 0; c < 4; ++c) {
          float4 w0 = *reinterpret_cast<const float4*>(&WcB[(kk + c) * 132 + jq]);
          float4 w1 = *reinterpret_cast<const float4*>(&WcB[(kk + c) * 132 + 64 + jq]);
#pragma unroll
          for (int r = 0; r < 4; ++r) {
            float a = av[r][c];
            acc[r][0] += a * w0.x; acc[r][1] += a * w0.y; acc[r][2] += a * w0.z; acc[r][3] += a * w0.w;
            acc[r][4] += a * w1.x; acc[r][5] += a * w1.y; acc[r][6] += a * w1.z; acc[r][7] += a * w1.w;
          }
        }
      }
    }
#pragma unroll
    for (int r = 0; r < 4; ++r) {
      *reinterpret_cast<float4*>(&hL[(i0 + r) * 132 + jq]) =
          make_float4(acc[r][0], acc[r][1], acc[r][2], acc[r][3]);
      *reinterpret_cast<float4*>(&hL[(i0 + r) * 132 + 64 + jq]) =
          make_float4(acc[r][4], acc[r][5], acc[r][6], acc[r][7]);
    }
    __syncthreads();   // hL complete; featL reads done

    // gather: featL[d][f] = b[f] + dd*(dd*h[d][f] + sum_s dinv[s]*h[s][f])
    // 4 threads/node; thread's cols = 4l + 16u (u=0..7) -> distinct banks
    {
      int d = t >> 2, l4 = (t & 3) * 4;
      float dd = dvL[d];
      float4 a[8];
#pragma unroll
      for (int u = 0; u < 8; ++u) {
        float4 hv = *reinterpret_cast<const float4*>(&hL[d * 132 + l4 + 16 * u]);
        a[u] = make_float4(dd * hv.x, dd * hv.y, dd * hv.z, dd * hv.w);
      }
      int o0 = oL[d], o1 = enL[d];
      for (int j = o0; j < o1; ++j) {
        int s = (j < EMAX) ? eLbuf[j] : (csrg[e_base + j] - nb);
        float w = dvL[s];
#pragma unroll
        for (int u = 0; u < 8; ++u) {
          float4 hv = *reinterpret_cast<const float4*>(&hL[s * 132 + l4 + 16 * u]);
          a[u].x += w * hv.x; a[u].y += w * hv.y; a[u].z += w * hv.z; a[u].w += w * hv.w;
        }
      }
#pragma unroll
      for (int u = 0; u < 8; ++u) {
        float4 bl = *reinterpret_cast<const float4*>(&bL[l4 + 16 * u]);
        float4 o = make_float4(bl.x + dd * a[u].x, bl.y + dd * a[u].y,
                               bl.z + dd * a[u].z, bl.w + dd * a[u].w);
        *reinterpret_cast<float4*>(&featL[d * 132 + l4 + 16 * u]) = o;
        if (l == 2)
          *reinterpret_cast<float4*>(&f3G[(size_t)(nb + d) * FDIM + l4 + 16 * u]) = o;
      }
    }
    __syncthreads();   // featL complete

    POOL_LAYER(l + 1)
  }
#undef POOL_LAYER
}

// ---------------------------------------------------------------- dense mm (affinity Y only)
template <bool RELU_IN>
__global__ __launch_bounds__(256) void k_mm(const float* __restrict__ A,
                                            const float* __restrict__ W,
                                            float* __restrict__ out) {
  __shared__ float As[32][68];    // [k][row], padded
  __shared__ float Ws[32][132];   // [k][col], padded
  int t = threadIdx.x;
  int r0 = blockIdx.x * 64;
  int i0 = (t >> 4) * 4;
  int j0 = (t & 15) * 8;
  float acc[4][8] = {};
  for (int kc = 0; kc < FDIM; kc += 32) {
    __syncthreads();
#pragma unroll
    for (int qq = 0; qq < 2; ++qq) {
      int l = t + 256 * qq;
      int row = l >> 3, kq = (l & 7) << 2;
      float4 a = *reinterpret_cast<const float4*>(&A[(size_t)(r0 + row) * FDIM + kc + kq]);
      if (RELU_IN) {
        a.x = fmaxf(a.x, 0.f); a.y = fmaxf(a.y, 0.f);
        a.z = fmaxf(a.z, 0.f); a.w = fmaxf(a.w, 0.f);
      }
      As[kq + 0][row] = a.x; As[kq + 1][row] = a.y;
      As[kq + 2][row] = a.z; As[kq + 3][row] = a.w;
    }
#pragma unroll
    for (int qq = 0; qq < 4; ++qq) {
      int l = t + 256 * qq;
      int row = l >> 5, c4 = (l & 31) << 2;
      *reinterpret_cast<float4*>(&Ws[row][c4]) =
          *reinterpret_cast<const float4*>(&W[(size_t)(kc + row) * FDIM + c4]);
    }
    __syncthreads();
#pragma unroll
    for (int kk = 0; kk < 32; ++kk) {
      float4 a4 = *reinterpret_cast<const float4*>(&As[kk][i0]);
      float4 wa = *reinterpret_cast<const float4*>(&Ws[kk][j0]);
      float4 wb = *reinterpret_cast<const float4*>(&Ws[kk][j0 + 4]);
      float av[4] = {a4.x, a4.y, a4.z, a4.w};
      float wv[8] = {wa.x, wa.y, wa.z, wa.w, wb.x, wb.y, wb.z, wb.w};
#pragma unroll
      for (int ii = 0; ii < 4; ++ii)
#pragma unroll
        for (int jj = 0; jj < 8; ++jj)
          acc[ii][jj] += av[ii] * wv[jj];
    }
  }
#pragma unroll
  for (int ii = 0; ii < 4; ++ii) {
    float4 o0 = make_float4(acc[ii][0], acc[ii][1], acc[ii][2], acc[ii][3]);
    float4 o1 = make_float4(acc[ii][4], acc[ii][5], acc[ii][6], acc[ii][7]);
    float* dst = &out[(size_t)(r0 + i0 + ii) * FDIM + j0];
    *reinterpret_cast<float4*>(dst) = o0;
    *reinterpret_cast<float4*>(dst + 4) = o1;
  }
}

// ---------------------------------------------------------------- affinity S[b] = Y[b] @ X[b]^T
__global__ __launch_bounds__(256) void k_affS(const float* __restrict__ Y,
                                              const float* __restrict__ X,
                                              float* __restrict__ S) {
  __shared__ float Ys[32][68];
  __shared__ float Xs[32][132];
  int t = threadIdx.x;
  int b = blockIdx.x >> 1;
  int ib = (blockIdx.x & 1) * 64;
  const float* Yb = Y + (size_t)b * NNODE * FDIM + (size_t)ib * FDIM;
  const float* Xb = X + (size_t)b * NNODE * FDIM;
  float* Sb = S + (size_t)b * NNODE * NNODE;
  int i0 = (t >> 4) * 4;
  int j0 = (t & 15) * 8;
  float acc[4][8] = {};
  for (int kc = 0; kc < FDIM; kc += 32) {
    __syncthreads();
#pragma unroll
    for (int qq = 0; qq < 2; ++qq) {
      int l = t + 256 * qq;
      int row = l >> 3, kq = (l & 7) << 2;
      float4 y = *reinterpret_cast<const float4*>(&Yb[(size_t)row * FDIM + kc + kq]);
      Ys[kq + 0][row] = y.x; Ys[kq + 1][row] = y.y;
      Ys[kq + 2][row] = y.z; Ys[kq + 3][row] = y.w;
    }
#pragma unroll
    for (int qq = 0; qq < 4; ++qq) {
      int l = t + 256 * qq;
      int row = l >> 3, kq = (l & 7) << 2;
      float4 xv = *reinterpret_cast<const float4*>(&Xb[(size_t)row * FDIM + kc + kq]);
      Xs[kq + 0][row] = xv.x; Xs[kq + 1][row] = xv.y;
      Xs[kq + 2][row] = xv.z; Xs[kq + 3][row] = xv.w;
    }
    __syncthreads();
#pragma unroll
    for (int kk = 0; kk < 32; ++kk) {
      float4 y4 = *reinterpret_cast<const float4*>(&Ys[kk][i0]);
      float4 xa = *reinterpret_cast<const float4*>(&Xs[kk][j0]);
      float4 xb = *reinterpret_cast<const float4*>(&Xs[kk][j0 + 4]);
      float yv[4] = {y4.x, y4.y, y4.z, y4.w};
      float xv[8] = {xa.x, xa.y, xa.z, xa.w, xb.x, xb.y, xb.z, xb.w};
#pragma unroll
      for (int ii = 0; ii < 4; ++ii)
#pragma unroll
        for (int jj = 0; jj < 8; ++jj)
          acc[ii][jj] += yv[ii] * xv[jj];
    }
  }
#pragma unroll
  for (int ii = 0; ii < 4; ++ii) {
    float4 o0 = make_float4(acc[ii][0], acc[ii][1], acc[ii][2], acc[ii][3]);
    float4 o1 = make_float4(acc[ii][4], acc[ii][5], acc[ii][6], acc[ii][7]);
    float* dst = &Sb[(size_t)(ib + i0 + ii) * NNODE + j0];
    *reinterpret_cast<float4*>(dst) = o0;
    *reinterpret_cast<float4*>(dst + 4) = o1;
  }
}

// ---------------------------------------------------------------- sinkhorn soft-topk (linear domain)
__global__ __launch_bounds__(1024) void k_sinkhorn(float* __restrict__ S,
                                                   const int* __restrict__ topk) {
  const int L = NNODE * NNODE;
  int b = blockIdx.x, t = threadIdx.x;
  int wave = t >> 6, lane = t & 63;
  float* x = S + (size_t)b * L;

  __shared__ float rA[16], rB[16];
  __shared__ float bc[2];

  float xv[16];
#pragma unroll
  for (int u = 0; u < 16; ++u) xv[u] = x[t + 1024 * u];

  {
    float mn = xv[0], mx = xv[0];
#pragma unroll
    for (int u = 1; u < 16; ++u) { mn = fminf(mn, xv[u]); mx = fmaxf(mx, xv[u]); }
    for (int off = 32; off; off >>= 1) {
      mn = fminf(mn, __shfl_down(mn, off));
      mx = fmaxf(mx, __shfl_down(mx, off));
    }
    if (lane == 0) { rA[wave] = mn; rB[wave] = mx; }
    __syncthreads();
    if (t < 16) {
      mn = rA[t]; mx = rB[t];
      for (int off = 8; off; off >>= 1) {
        mn = fminf(mn, __shfl_down(mn, off));
        mx = fmaxf(mx, __shfl_down(mx, off));
      }
      if (t == 0) { bc[0] = mn - 1.f; bc[1] = mx + 1.f; }
    }
    __syncthreads();
  }
  float a_lo = bc[0], a_hi = bc[1];

  float p[16], q[16];
#pragma unroll
  for (int u = 0; u < 16; ++u) {
    p[u] = __expf(a_lo - xv[u]);
    q[u] = __expf(xv[u] - a_hi);
  }

  const float Lf = (float)L;
  float kk = 0.5f * (float)topk[0];

  float E0 = 1.f, E1 = 1.f, E0p = 1.f, E1p = 1.f;
  for (int it = 0; it < 6; ++it) {
    E0p = E0; E1p = E1;
    float r0 = 0.f, r1 = 0.f;
#pragma unroll
    for (int u = 0; u < 16; ++u) {
      float denom = fmaf(p[u], E0, q[u] * E1);
      float rin = __builtin_amdgcn_rcpf(denom);
      r0 = fmaf(p[u], rin, r0);
      r1 = fmaf(q[u], rin, r1);
    }
    for (int off = 32; off; off >>= 1) {
      r0 += __shfl_down(r0, off);
      r1 += __shfl_down(r1, off);
    }
    if (lane == 0) { rA[wave] = r0; rB[wave] = r1; }
    __syncthreads();
    if (t < 16) {
      r0 = rA[t]; r1 = rB[t];
      for (int off = 8; off; off >>= 1) {
        r0 += __shfl_down(r0, off);
        r1 += __shfl_down(r1, off);
      }
      if (t == 0) { bc[0] = (Lf - kk) / r0; bc[1] = kk / r1; }
    }
    __syncthreads();
    E0 = bc[0]; E1 = bc[1];
    __syncthreads();
  }

#pragma unroll
  for (int u = 0; u < 16; ++u) {
    float denom = fmaf(p[u], E0p, q[u] * E1p);
    x[t + 1024 * u] = q[u] * E1 * __builtin_amdgcn_rcpf(denom);
  }
}

// ---------------------------------------------------------------- scoring MLP
__global__ __launch_bounds__(256) void k_mlp(const float* __restrict__ gfs,
                                             const float* __restrict__ W1,
                                             const float* __restrict__ b1,
                                             const float* __restrict__ W2,
                                             const float* __restrict__ b2,
                                             float* __restrict__ ged) {
  __shared__ float sm[1024];
  int b = blockIdx.x, t = threadIdx.x;
  const float* s = gfs + b * 1024;
#pragma unroll
  for (int qq = 0; qq < 4; ++qq) sm[t + 256 * qq] = s[t + 256 * qq];
  __syncthreads();
  int j4 = (t & 15) * 4, kp = t >> 4;
  float4 acc = make_float4(0.f, 0.f, 0.f, 0.f);
#pragma unroll 8
  for (int k = 0; k < 64; ++k) {
    float4 w = *reinterpret_cast<const float4*>(&W1[(size_t)(kp * 64 + k) * 64 + j4]);
    float sv = sm[kp * 64 + k];
    acc.x += sv * w.x; acc.y += sv * w.y; acc.z += sv * w.z; acc.w += sv * w.w;
  }
  __syncthreads();
  *reinterpret_cast<float4*>(&sm[kp * 64 + j4]) = acc;
  __syncthreads();
  if (t < 64) {
    float h = b1[t];
#pragma unroll
    for (int kp2 = 0; kp2 < 16; ++kp2) h += sm[kp2 * 64 + t];
    h = fmaxf(h, 0.f);
    float v = h * W2[t];
    for (int off = 32; off; off >>= 1) v += __shfl_down(v, off);
    if (t == 0) ged[b] = 1.f / (1.f + __expf(-(v + b2[0])));
  }
}

// ================================================================ launch
extern "C" void kernel_launch(void* const* d_in, const int* in_sizes, int n_in,
                              void* d_out, int out_size, void* d_ws, size_t ws_size,
                              hipStream_t stream) {
  (void)in_sizes; (void)n_in; (void)out_size; (void)ws_size;
  const float* x1    = (const float*)d_in[0];
  const int*   cent1 = (const int*)  d_in[1];
  const float* rw1   = (const float*)d_in[2];
  const int*   src1  = (const int*)  d_in[3];
  const int*   dst1  = (const int*)  d_in[4];
  const float* x2    = (const float*)d_in[5];
  const int*   cent2 = (const int*)  d_in[6];
  const float* rw2   = (const float*)d_in[7];
  const int*   src2  = (const int*)  d_in[8];
  const int*   dst2  = (const int*)  d_in[9];
  const float* demb  = (const float*)d_in[10];
  const float* initW = (const float*)d_in[11];
  const float* initb = (const float*)d_in[12];
  const float* W1    = (const float*)d_in[13];
  const float* b1    = (const float*)d_in[14];
  const float* W2    = (const float*)d_in[15];
  const float* b2    = (const float*)d_in[16];
  const float* W3    = (const float*)d_in[17];
  const float* b3    = (const float*)d_in[18];
  const float* Aaff  = (const float*)d_in[19];
  const float* scW1  = (const float*)d_in[20];
  const float* scb1  = (const float*)d_in[21];
  const float* scW2  = (const float*)d_in[22];
  const float* scb2  = (const float*)d_in[23];
  const int*   topk  = (const int*)  d_in[24];

  float* ws    = (float*)d_ws;
  float* feat1 = ws;
  float* feat2 = ws + (size_t)1 * NTF;
  float* f13   = ws + (size_t)2 * NTF;
  float* f23   = ws + (size_t)3 * NTF;
  float* htmp  = ws + (size_t)4 * NTF;
  float* dinv1 = ws + (size_t)5 * NTF;
  float* dinv2 = dinv1 + NT;
  float* gfs   = dinv2 + NT;

  float* ged = (float*)d_out;
  float* S1  = ged + BATCH;
  float* S2  = S1 + (size_t)BATCH * NNODE * NNODE;

  // int scratch lives in S1's output region (only written by affS AFTER chain)
  int* degi1 = (int*)S1;
  int* ofs1  = degi1 + NT;
  int* cur1  = ofs1 + NT;
  int* csr1  = cur1 + NT;
  int* degi2 = csr1 + NEDGE;
  int* ofs2  = degi2 + NT;
  int* cur2  = ofs2 + NT;
  int* csr2  = cur2 + NT;

  const int gMM = NT / 64;   // 512 blocks
  const int gE  = NEDGE / 256;
  const int gN  = NT / 256;

  // CSR + degree norms
  k_zero_i<<<gN, 256, 0, stream>>>(degi1, NT);
  k_zero_i<<<gN, 256, 0, stream>>>(degi2, NT);
  k_deg_count<<<gE, 256, 0, stream>>>(dst1, degi1);
  k_deg_count<<<gE, 256, 0, stream>>>(dst2, degi2);
  k_dinv<<<gN, 256, 0, stream>>>(degi1, dinv1, NT);
  k_dinv<<<gN, 256, 0, stream>>>(degi2, dinv2, NT);
  k_scan<<<1, 1024, 0, stream>>>(degi1, ofs1, cur1);
  k_scan<<<1, 1024, 0, stream>>>(degi2, ofs2, cur2);
  k_csr_fill<<<gE, 256, 0, stream>>>(src1, dst1, cur1, csr1);
  k_csr_fill<<<gE, 256, 0, stream>>>(src2, dst2, cur2, csr2);

  // fused conv chains (both sides), writes feat1/feat2/f13/f23/gfs
  k_chain<<<512, 512, 0, stream>>>(
      x1, cent1, rw1, x2, cent2, rw2, demb, initW, initb,
      W1, b1, W2, b2, W3, b3,
      ofs1, cur1, csr1, ofs2, cur2, csr2, dinv1, dinv2,
      feat1, feat2, f13, f23, gfs);

  // sim1
  k_mm<false><<<gMM, 256, 0, stream>>>(feat1, Aaff, htmp);
  k_affS<<<BATCH * 2, 256, 0, stream>>>(htmp, feat2, S1);
  k_sinkhorn<<<BATCH, 1024, 0, stream>>>(S1, topk);

  // sim2
  k_mm<false><<<gMM, 256, 0, stream>>>(f13, Aaff, htmp);
  k_affS<<<BATCH * 2, 256, 0, stream>>>(htmp, f23, S2);
  k_sinkhorn<<<BATCH, 1024, 0, stream>>>(S2, topk);

  // ged
  k_mlp<<<BATCH, 256, 0, stream>>>(gfs, scW1, scb1, scW2, scb2, ged);
}

// Round 9
// 537.233 us; speedup vs baseline: 1.8699x; 1.8699x over previous
//
#include <hip/hip_runtime.h>
#include <math.h>

#define BATCH 256
#define NNODE 128
#define NT    32768      // BATCH*NNODE
#define FDIM  128
#define NEDGE 262144
#define LBL   29
#define MAXDEG 16
#define RWD   16
#define NTF   (NT * FDIM)
#define EMAX  1408       // per-graph edge buffer (mean 1024, sigma ~32; fallback past this)

// ---------------------------------------------------------------- CSR build
__global__ void k_zero_i(int* __restrict__ p, int n) {
  int i = blockIdx.x * 256 + threadIdx.x;
  if (i < n) p[i] = 0;
}
__global__ void k_deg_count(const int* __restrict__ dst, int* __restrict__ degi) {
  int e = blockIdx.x * 256 + threadIdx.x;
  if (e < NEDGE) atomicAdd(&degi[dst[e]], 1);
}
__global__ void k_dinv(const int* __restrict__ degi, float* __restrict__ dinv, int n) {
  int i = blockIdx.x * 256 + threadIdx.x;
  if (i < n) dinv[i] = rsqrtf((float)(degi[i] + 1));   // +1 self loop
}
__global__ __launch_bounds__(1024) void k_scan(const int* __restrict__ degi,
                                               int* __restrict__ ofs,
                                               int* __restrict__ cur) {
  __shared__ int part[1024];
  int t = threadIdx.x;
  int base = t * 32;
  int loc[32]; int sum = 0;
#pragma unroll
  for (int u = 0; u < 32; ++u) { loc[u] = sum; sum += degi[base + u]; }
  part[t] = sum;
  __syncthreads();
  for (int off = 1; off < 1024; off <<= 1) {
    int v = (t >= off) ? part[t - off] : 0;
    __syncthreads();
    part[t] += v;
    __syncthreads();
  }
  int excl = (t == 0) ? 0 : part[t - 1];
#pragma unroll
  for (int u = 0; u < 32; ++u) {
    int o = excl + loc[u];
    ofs[base + u] = o; cur[base + u] = o;
  }
}
__global__ void k_csr_fill(const int* __restrict__ src, const int* __restrict__ dst,
                           int* __restrict__ cur, int* __restrict__ csr) {
  int e = blockIdx.x * 256 + threadIdx.x;
  if (e < NEDGE) {
    int pos = atomicAdd(&cur[dst[e]], 1);
    csr[pos] = src[e];
  }
}

// ---------------------------------------------------------------- fused per-graph chain
// One block = one (graph, side). 256 threads (proven no-spill: R6 VGPR=132,
// FETCH 9 MB; every 512-thread variant spills GBs regardless of
// __launch_bounds__ -- R5/R7/R8). Conflict-free LDS maps (ported from R7's
// measured 5.4x conflict cut):
//  * A-reads: per-thread rows {g, g+32, g+64, g+96}, g=t>>3 -> per wave the 8
//    g's are consecutive -> banks 4g distinct, 8-lane broadcast = free.
//  * W-reads: col quads {jq, 32+jq, 64+jq, 96+jq}, jq=(t&7)*4 -> each read is
//    8 lanes x 4 contiguous dwords = 32 dwords = every bank once = free.
__global__ __launch_bounds__(256) void k_chain(
    const float* __restrict__ x1, const int* __restrict__ cent1, const float* __restrict__ rw1,
    const float* __restrict__ x2, const int* __restrict__ cent2, const float* __restrict__ rw2,
    const float* __restrict__ demb,
    const float* __restrict__ initW, const float* __restrict__ initb,
    const float* __restrict__ W1, const float* __restrict__ b1,
    const float* __restrict__ W2, const float* __restrict__ b2,
    const float* __restrict__ W3, const float* __restrict__ b3,
    const int* __restrict__ ofs1, const int* __restrict__ end1, const int* __restrict__ csr1,
    const int* __restrict__ ofs2, const int* __restrict__ end2, const int* __restrict__ csr2,
    const float* __restrict__ dinv1, const float* __restrict__ dinv2,
    float* __restrict__ feat1G, float* __restrict__ feat2G,
    float* __restrict__ f13G, float* __restrict__ f23G,
    float* __restrict__ gfs) {
  __shared__ float featL[128 * 132];
  __shared__ float hL[128 * 132];     // phase 0: concat overlay [128*68]
  __shared__ float WcB[32 * 132];     // pool tmp overlay [8*128]
  __shared__ float dvL[128];
  __shared__ float bL[128];
  __shared__ int   oL[128], enL[128];
  __shared__ int   eLbuf[EMAX];

  const int t = threadIdx.x;
  const int side = blockIdx.x >> 8;
  const int g = blockIdx.x & 255;
  const int nb = g * NNODE;

  const float* xg    = side ? x2 : x1;
  const int*   centg = side ? cent2 : cent1;
  const float* rwg   = side ? rw2 : rw1;
  const int*   ofsg  = side ? ofs2 : ofs1;
  const int*   endg  = side ? end2 : end1;
  const int*   csrg  = side ? csr2 : csr1;
  const float* dinvg = side ? dinv2 : dinv1;
  float* featG = side ? feat2G : feat1G;
  float* f3G   = side ? f23G : f13G;

  // -------- phase -1: stage dinv / csr offsets / edge list / concat features
  const int e_base = ofsg[nb];
  const int e_cnt  = endg[nb + NNODE - 1] - e_base;
  if (t < 128) {
    dvL[t] = dinvg[nb + t];
    oL[t]  = ofsg[nb + t] - e_base;
    enL[t] = endg[nb + t] - e_base;
  }
  for (int idx = t; idx < e_cnt; idx += 256)
    if (idx < EMAX) eLbuf[idx] = csrg[e_base + idx] - nb;
  {
    int d = t >> 1, sub = t & 1;          // 2 threads per node, 34 cols each
    int node = nb + d;
    int ct = centg[node];
    const float* xr = xg + (size_t)node * LBL;
    const float* er = demb + ct * MAXDEG;
    const float* rr = rwg + (size_t)node * RWD;
    float* cL = hL;   // concat overlay [128][68]
    for (int c = sub * 34; c < sub * 34 + 34; ++c) {
      float v = 0.f;
      if (c < LBL) v = xr[c];
      else if (c < LBL + MAXDEG) v = er[c - LBL];
      else if (c < 61) v = rr[c - 45];
      cL[d * 68 + c] = v;
    }
  }
  __syncthreads();

  const int rg = t >> 3;           // row base; thread rows rg + 32*r
  const int jq = (t & 7) * 4;      // col quads jq + 32*q

  // -------- phase 0: featL = relu(concat @ initW + initb); write featG; pool layer0
  {
    float acc[4][16] = {};
    const float* cL = hL;
    for (int kc = 0; kc < 64; kc += 32) {
      __syncthreads();
#pragma unroll
      for (int u = 0; u < 4; ++u) {
        int ll = t + 256 * u;                  // 0..1023
        int row = ll >> 5, c4 = (ll & 31) * 4;
        int gk = kc + row;
        float4 w = (gk < 61) ? *reinterpret_cast<const float4*>(&initW[(size_t)gk * FDIM + c4])
                             : make_float4(0.f, 0.f, 0.f, 0.f);
        *reinterpret_cast<float4*>(&WcB[row * 132 + c4]) = w;
      }
      if (kc == 0 && t < 128) bL[t] = initb[t];
      __syncthreads();
      for (int kk = 0; kk < 32; kk += 4) {
        float av[4][4];
#pragma unroll
        for (int r = 0; r < 4; ++r) {
          float4 tmp = *reinterpret_cast<const float4*>(&cL[(rg + 32 * r) * 68 + kc + kk]);
          av[r][0] = tmp.x; av[r][1] = tmp.y; av[r][2] = tmp.z; av[r][3] = tmp.w;
        }
#pragma unroll
        for (int c = 0; c < 4; ++c) {
          float4 w0 = *reinterpret_cast<const float4*>(&WcB[(kk + c) * 132 + jq]);
          float4 w1 = *reinterpret_cast<const float4*>(&WcB[(kk + c) * 132 + 32 + jq]);
          float4 w2 = *reinterpret_cast<const float4*>(&WcB[(kk + c) * 132 + 64 + jq]);
          float4 w3 = *reinterpret_cast<const float4*>(&WcB[(kk + c) * 132 + 96 + jq]);
#pragma unroll
          for (int r = 0; r < 4; ++r) {
            float a = av[r][c];
            acc[r][0]  += a * w0.x; acc[r][1]  += a * w0.y; acc[r][2]  += a * w0.z; acc[r][3]  += a * w0.w;
            acc[r][4]  += a * w1.x; acc[r][5]  += a * w1.y; acc[r][6]  += a * w1.z; acc[r][7]  += a * w1.w;
            acc[r][8]  += a * w2.x; acc[r][9]  += a * w2.y; acc[r][10] += a * w2.z; acc[r][11] += a * w2.w;
            acc[r][12] += a * w3.x; acc[r][13] += a * w3.y; acc[r][14] += a * w3.z; acc[r][15] += a * w3.w;
          }
        }
      }
    }
    __syncthreads();
#pragma unroll
    for (int r = 0; r < 4; ++r) {
      int row = rg + 32 * r;
#pragma unroll
      for (int q = 0; q < 4; ++q) {
        int col = q * 32 + jq;
        float4 bl = *reinterpret_cast<const float4*>(&bL[col]);
        float4 o = make_float4(fmaxf(acc[r][q * 4 + 0] + bl.x, 0.f),
                               fmaxf(acc[r][q * 4 + 1] + bl.y, 0.f),
                               fmaxf(acc[r][q * 4 + 2] + bl.z, 0.f),
                               fmaxf(acc[r][q * 4 + 3] + bl.w, 0.f));
        *reinterpret_cast<float4*>(&featL[row * 132 + col]) = o;
        *reinterpret_cast<float4*>(&featG[(size_t)(nb + row) * FDIM + col]) = o;
      }
    }
    __syncthreads();
  }

  // -------- pool helper (256 threads: 8 row-groups x 16 rows)
#define POOL_LAYER(layer)                                                            \
  {                                                                                  \
    int j4 = (t & 31) * 4, qq = t >> 5;                                              \
    float4 pv = side ? make_float4(-INFINITY, -INFINITY, -INFINITY, -INFINITY)       \
                     : make_float4(0.f, 0.f, 0.f, 0.f);                              \
    for (int r = 0; r < 16; ++r) {                                                   \
      float4 fv = *reinterpret_cast<const float4*>(&featL[(qq * 16 + r) * 132 + j4]);\
      if (side) { pv.x = fmaxf(pv.x, fv.x); pv.y = fmaxf(pv.y, fv.y);                \
                  pv.z = fmaxf(pv.z, fv.z); pv.w = fmaxf(pv.w, fv.w); }              \
      else      { pv.x += fv.x; pv.y += fv.y; pv.z += fv.z; pv.w += fv.w; }          \
    }                                                                                \
    *reinterpret_cast<float4*>(&WcB[qq * 128 + j4]) = pv;                            \
    __syncthreads();                                                                 \
    if (t < 128) {                                                                   \
      float v = side ? -INFINITY : 0.f;                                              \
      for (int q2 = 0; q2 < 8; ++q2) {                                               \
        float w2 = WcB[q2 * 128 + t];                                                \
        v = side ? fmaxf(v, w2) : (v + w2);                                          \
      }                                                                              \
      gfs[g * 1024 + side * 512 + (layer) * 128 + t] = v;                            \
    }                                                                                \
  }

  POOL_LAYER(0)

  // -------- 3 conv layers
  for (int l = 0; l < 3; ++l) {
    const float* Wg = (l == 0) ? W1 : (l == 1) ? W2 : W3;   // SGPR select
    const float* bg = (l == 0) ? b1 : (l == 1) ? b2 : b3;
    // mm: hL = (l>0 ? relu(featL) : featL) @ W_l
    float acc[4][16] = {};
    for (int kc = 0; kc < 128; kc += 32) {
      __syncthreads();   // protects WcB (pool tmp / prev chunk)
#pragma unroll
      for (int u = 0; u < 4; ++u) {
        int ll = t + 256 * u;
        int row = ll >> 5, c4 = (ll & 31) * 4;
        *reinterpret_cast<float4*>(&WcB[row * 132 + c4]) =
            *reinterpret_cast<const float4*>(&Wg[(size_t)(kc + row) * FDIM + c4]);
      }
      if (kc == 0 && t < 128) bL[t] = bg[t];
      __syncthreads();
      for (int kk = 0; kk < 32; kk += 4) {
        float av[4][4];
#pragma unroll
        for (int r = 0; r < 4; ++r) {
          float4 tmp = *reinterpret_cast<const float4*>(&featL[(rg + 32 * r) * 132 + kc + kk]);
          if (l > 0) {
            tmp.x = fmaxf(tmp.x, 0.f); tmp.y = fmaxf(tmp.y, 0.f);
            tmp.z = fmaxf(tmp.z, 0.f); tmp.w = fmaxf(tmp.w, 0.f);
          }
          av[r][0] = tmp.x; av[r][1] = tmp.y; av[r][2] = tmp.z; av[r][3] = tmp.w;
        }
#pragma unroll
        for (int c = 0; c < 4; ++c) {
          float4 w0 = *reinterpret_cast<const float4*>(&WcB[(kk + c) * 132 + jq]);
          float4 w1 = *reinterpret_cast<const float4*>(&WcB[(kk + c) * 132 + 32 + jq]);
          float4 w2 = *reinterpret_cast<const float4*>(&WcB[(kk + c) * 132 + 64 + jq]);
          float4 w3 = *reinterpret_cast<const float4*>(&WcB[(kk + c) * 132 + 96 + jq]);
#pragma unroll
          for (int r = 0; r < 4; ++r) {
            float a = av[r][c];
            acc[r][0]  += a * w0.x; acc[r][1]  += a * w0.y; acc[r][2]  += a * w0.z; acc[r][3]  += a * w0.w;
            acc[r][4]  += a * w1.x; acc[r][5]  += a * w1.y; acc[r][6]  += a * w1.z; acc[r][7]  += a * w1.w;
            acc[r][8]  += a * w2.x; acc[r][9]  += a * w2.y; acc[r][10] += a * w2.z; acc[r][11] += a * w2.w;
            acc[r][12] += a * w3.x; acc[r][13] += a * w3.y; acc[r][14] += a * w3.z; acc[r][15] += a * w3.w;
          }
        }
      }
    }
#pragma unroll
    for (int r = 0; r < 4; ++r) {
      int row = rg + 32 * r;
#pragma unroll
      for (int q = 0; q < 4; ++q) {
        int col = q * 32 + jq;
        *reinterpret_cast<float4*>(&hL[row * 132 + col]) =
            make_float4(acc[r][q * 4 + 0], acc[r][q * 4 + 1],
                        acc[r][q * 4 + 2], acc[r][q * 4 + 3]);
      }
    }
    __syncthreads();   // hL complete; featL reads done

    // gather: featL[d][f] = b[f] + dd*(dd*h[d][f] + sum_s dinv[s]*h[s][f])
    {
      int d = t >> 1, fc = (t & 1) * 64;   // 2 threads/node, 64 cols each
      float dd = dvL[d];
      float4 a[16];
#pragma unroll
      for (int u = 0; u < 16; ++u) {
        float4 hv = *reinterpret_cast<const float4*>(&hL[d * 132 + fc + u * 4]);
        a[u] = make_float4(dd * hv.x, dd * hv.y, dd * hv.z, dd * hv.w);
      }
      int o0 = oL[d], o1 = enL[d];
      for (int j = o0; j < o1; ++j) {
        int s = (j < EMAX) ? eLbuf[j] : (csrg[e_base + j] - nb);
        float w = dvL[s];
#pragma unroll
        for (int u = 0; u < 16; ++u) {
          float4 hv = *reinterpret_cast<const float4*>(&hL[s * 132 + fc + u * 4]);
          a[u].x += w * hv.x; a[u].y += w * hv.y; a[u].z += w * hv.z; a[u].w += w * hv.w;
        }
      }
#pragma unroll
      for (int u = 0; u < 16; ++u) {
        float4 bl = *reinterpret_cast<const float4*>(&bL[fc + u * 4]);
        float4 o = make_float4(bl.x + dd * a[u].x, bl.y + dd * a[u].y,
                               bl.z + dd * a[u].z, bl.w + dd * a[u].w);
        *reinterpret_cast<float4*>(&featL[d * 132 + fc + u * 4]) = o;
        if (l == 2)
          *reinterpret_cast<float4*>(&f3G[(size_t)(nb + d) * FDIM + fc + u * 4]) = o;
      }
    }
    __syncthreads();   // featL complete

    POOL_LAYER(l + 1)
  }
#undef POOL_LAYER
}

// ---------------------------------------------------------------- dense mm (affinity Y only)
template <bool RELU_IN>
__global__ __launch_bounds__(256) void k_mm(const float* __restrict__ A,
                                            const float* __restrict__ W,
                                            float* __restrict__ out) {
  __shared__ float As[32][68];    // [k][row], padded
  __shared__ float Ws[32][132];   // [k][col], padded
  int t = threadIdx.x;
  int r0 = blockIdx.x * 64;
  int i0 = (t >> 4) * 4;
  int j0 = (t & 15) * 8;
  float acc[4][8] = {};
  for (int kc = 0; kc < FDIM; kc += 32) {
    __syncthreads();
#pragma unroll
    for (int qq = 0; qq < 2; ++qq) {
      int l = t + 256 * qq;
      int row = l >> 3, kq = (l & 7) << 2;
      float4 a = *reinterpret_cast<const float4*>(&A[(size_t)(r0 + row) * FDIM + kc + kq]);
      if (RELU_IN) {
        a.x = fmaxf(a.x, 0.f); a.y = fmaxf(a.y, 0.f);
        a.z = fmaxf(a.z, 0.f); a.w = fmaxf(a.w, 0.f);
      }
      As[kq + 0][row] = a.x; As[kq + 1][row] = a.y;
      As[kq + 2][row] = a.z; As[kq + 3][row] = a.w;
    }
#pragma unroll
    for (int qq = 0; qq < 4; ++qq) {
      int l = t + 256 * qq;
      int row = l >> 5, c4 = (l & 31) << 2;
      *reinterpret_cast<float4*>(&Ws[row][c4]) =
          *reinterpret_cast<const float4*>(&W[(size_t)(kc + row) * FDIM + c4]);
    }
    __syncthreads();
#pragma unroll
    for (int kk = 0; kk < 32; ++kk) {
      float4 a4 = *reinterpret_cast<const float4*>(&As[kk][i0]);
      float4 wa = *reinterpret_cast<const float4*>(&Ws[kk][j0]);
      float4 wb = *reinterpret_cast<const float4*>(&Ws[kk][j0 + 4]);
      float av[4] = {a4.x, a4.y, a4.z, a4.w};
      float wv[8] = {wa.x, wa.y, wa.z, wa.w, wb.x, wb.y, wb.z, wb.w};
#pragma unroll
      for (int ii = 0; ii < 4; ++ii)
#pragma unroll
        for (int jj = 0; jj < 8; ++jj)
          acc[ii][jj] += av[ii] * wv[jj];
    }
  }
#pragma unroll
  for (int ii = 0; ii < 4; ++ii) {
    float4 o0 = make_float4(acc[ii][0], acc[ii][1], acc[ii][2], acc[ii][3]);
    float4 o1 = make_float4(acc[ii][4], acc[ii][5], acc[ii][6], acc[ii][7]);
    float* dst = &out[(size_t)(r0 + i0 + ii) * FDIM + j0];
    *reinterpret_cast<float4*>(dst) = o0;
    *reinterpret_cast<float4*>(dst + 4) = o1;
  }
}

// ---------------------------------------------------------------- affinity S[b] = Y[b] @ X[b]^T
__global__ __launch_bounds__(256) void k_affS(const float* __restrict__ Y,
                                              const float* __restrict__ X,
                                              float* __restrict__ S) {
  __shared__ float Ys[32][68];
  __shared__ float Xs[32][132];
  int t = threadIdx.x;
  int b = blockIdx.x >> 1;
  int ib = (blockIdx.x & 1) * 64;
  const float* Yb = Y + (size_t)b * NNODE * FDIM + (size_t)ib * FDIM;
  const float* Xb = X + (size_t)b * NNODE * FDIM;
  float* Sb = S + (size_t)b * NNODE * NNODE;
  int i0 = (t >> 4) * 4;
  int j0 = (t & 15) * 8;
  float acc[4][8] = {};
  for (int kc = 0; kc < FDIM; kc += 32) {
    __syncthreads();
#pragma unroll
    for (int qq = 0; qq < 2; ++qq) {
      int l = t + 256 * qq;
      int row = l >> 3, kq = (l & 7) << 2;
      float4 y = *reinterpret_cast<const float4*>(&Yb[(size_t)row * FDIM + kc + kq]);
      Ys[kq + 0][row] = y.x; Ys[kq + 1][row] = y.y;
      Ys[kq + 2][row] = y.z; Ys[kq + 3][row] = y.w;
    }
#pragma unroll
    for (int qq = 0; qq < 4; ++qq) {
      int l = t + 256 * qq;
      int row = l >> 3, kq = (l & 7) << 2;
      float4 xv = *reinterpret_cast<const float4*>(&Xb[(size_t)row * FDIM + kc + kq]);
      Xs[kq + 0][row] = xv.x; Xs[kq + 1][row] = xv.y;
      Xs[kq + 2][row] = xv.z; Xs[kq + 3][row] = xv.w;
    }
    __syncthreads();
#pragma unroll
    for (int kk = 0; kk < 32; ++kk) {
      float4 y4 = *reinterpret_cast<const float4*>(&Ys[kk][i0]);
      float4 xa = *reinterpret_cast<const float4*>(&Xs[kk][j0]);
      float4 xb = *reinterpret_cast<const float4*>(&Xs[kk][j0 + 4]);
      float yv[4] = {y4.x, y4.y, y4.z, y4.w};
      float xv[8] = {xa.x, xa.y, xa.z, xa.w, xb.x, xb.y, xb.z, xb.w};
#pragma unroll
      for (int ii = 0; ii < 4; ++ii)
#pragma unroll
        for (int jj = 0; jj < 8; ++jj)
          acc[ii][jj] += yv[ii] * xv[jj];
    }
  }
#pragma unroll
  for (int ii = 0; ii < 4; ++ii) {
    float4 o0 = make_float4(acc[ii][0], acc[ii][1], acc[ii][2], acc[ii][3]);
    float4 o1 = make_float4(acc[ii][4], acc[ii][5], acc[ii][6], acc[ii][7]);
    float* dst = &Sb[(size_t)(ib + i0 + ii) * NNODE + j0];
    *reinterpret_cast<float4*>(dst) = o0;
    *reinterpret_cast<float4*>(dst + 4) = o1;
  }
}

// ---------------------------------------------------------------- sinkhorn soft-topk (linear domain)
__global__ __launch_bounds__(1024) void k_sinkhorn(float* __restrict__ S,
                                                   const int* __restrict__ topk) {
  const int L = NNODE * NNODE;
  int b = blockIdx.x, t = threadIdx.x;
  int wave = t >> 6, lane = t & 63;
  float* x = S + (size_t)b * L;

  __shared__ float rA[16], rB[16];
  __shared__ float bc[2];

  float xv[16];
#pragma unroll
  for (int u = 0; u < 16; ++u) xv[u] = x[t + 1024 * u];

  {
    float mn = xv[0], mx = xv[0];
#pragma unroll
    for (int u = 1; u < 16; ++u) { mn = fminf(mn, xv[u]); mx = fmaxf(mx, xv[u]); }
    for (int off = 32; off; off >>= 1) {
      mn = fminf(mn, __shfl_down(mn, off));
      mx = fmaxf(mx, __shfl_down(mx, off));
    }
    if (lane == 0) { rA[wave] = mn; rB[wave] = mx; }
    __syncthreads();
    if (t < 16) {
      mn = rA[t]; mx = rB[t];
      for (int off = 8; off; off >>= 1) {
        mn = fminf(mn, __shfl_down(mn, off));
        mx = fmaxf(mx, __shfl_down(mx, off));
      }
      if (t == 0) { bc[0] = mn - 1.f; bc[1] = mx + 1.f; }
    }
    __syncthreads();
  }
  float a_lo = bc[0], a_hi = bc[1];

  float p[16], q[16];
#pragma unroll
  for (int u = 0; u < 16; ++u) {
    p[u] = __expf(a_lo - xv[u]);
    q[u] = __expf(xv[u] - a_hi);
  }

  const float Lf = (float)L;
  float kk = 0.5f * (float)topk[0];

  float E0 = 1.f, E1 = 1.f, E0p = 1.f, E1p = 1.f;
  for (int it = 0; it < 6; ++it) {
    E0p = E0; E1p = E1;
    float r0 = 0.f, r1 = 0.f;
#pragma unroll
    for (int u = 0; u < 16; ++u) {
      float denom = fmaf(p[u], E0, q[u] * E1);
      float rin = __builtin_amdgcn_rcpf(denom);
      r0 = fmaf(p[u], rin, r0);
      r1 = fmaf(q[u], rin, r1);
    }
    for (int off = 32; off; off >>= 1) {
      r0 += __shfl_down(r0, off);
      r1 += __shfl_down(r1, off);
    }
    if (lane == 0) { rA[wave] = r0; rB[wave] = r1; }
    __syncthreads();
    if (t < 16) {
      r0 = rA[t]; r1 = rB[t];
      for (int off = 8; off; off >>= 1) {
        r0 += __shfl_down(r0, off);
        r1 += __shfl_down(r1, off);
      }
      if (t == 0) { bc[0] = (Lf - kk) / r0; bc[1] = kk / r1; }
    }
    __syncthreads();
    E0 = bc[0]; E1 = bc[1];
    __syncthreads();
  }

#pragma unroll
  for (int u = 0; u < 16; ++u) {
    float denom = fmaf(p[u], E0p, q[u] * E1p);
    x[t + 1024 * u] = q[u] * E1 * __builtin_amdgcn_rcpf(denom);
  }
}

// ---------------------------------------------------------------- scoring MLP
__global__ __launch_bounds__(256) void k_mlp(const float* __restrict__ gfs,
                                             const float* __restrict__ W1,
                                             const float* __restrict__ b1,
                                             const float* __restrict__ W2,
                                             const float* __restrict__ b2,
                                             float* __restrict__ ged) {
  __shared__ float sm[1024];
  int b = blockIdx.x, t = threadIdx.x;
  const float* s = gfs + b * 1024;
#pragma unroll
  for (int qq = 0; qq < 4; ++qq) sm[t + 256 * qq] = s[t + 256 * qq];
  __syncthreads();
  int j4 = (t & 15) * 4, kp = t >> 4;
  float4 acc = make_float4(0.f, 0.f, 0.f, 0.f);
#pragma unroll 8
  for (int k = 0; k < 64; ++k) {
    float4 w = *reinterpret_cast<const float4*>(&W1[(size_t)(kp * 64 + k) * 64 + j4]);
    float sv = sm[kp * 64 + k];
    acc.x += sv * w.x; acc.y += sv * w.y; acc.z += sv * w.z; acc.w += sv * w.w;
  }
  __syncthreads();
  *reinterpret_cast<float4*>(&sm[kp * 64 + j4]) = acc;
  __syncthreads();
  if (t < 64) {
    float h = b1[t];
#pragma unroll
    for (int kp2 = 0; kp2 < 16; ++kp2) h += sm[kp2 * 64 + t];
    h = fmaxf(h, 0.f);
    float v = h * W2[t];
    for (int off = 32; off; off >>= 1) v += __shfl_down(v, off);
    if (t == 0) ged[b] = 1.f / (1.f + __expf(-(v + b2[0])));
  }
}

// ================================================================ launch
extern "C" void kernel_launch(void* const* d_in, const int* in_sizes, int n_in,
                              void* d_out, int out_size, void* d_ws, size_t ws_size,
                              hipStream_t stream) {
  (void)in_sizes; (void)n_in; (void)out_size; (void)ws_size;
  const float* x1    = (const float*)d_in[0];
  const int*   cent1 = (const int*)  d_in[1];
  const float* rw1   = (const float*)d_in[2];
  const int*   src1  = (const int*)  d_in[3];
  const int*   dst1  = (const int*)  d_in[4];
  const float* x2    = (const float*)d_in[5];
  const int*   cent2 = (const int*)  d_in[6];
  const float* rw2   = (const float*)d_in[7];
  const int*   src2  = (const int*)  d_in[8];
  const int*   dst2  = (const int*)  d_in[9];
  const float* demb  = (const float*)d_in[10];
  const float* initW = (const float*)d_in[11];
  const float* initb = (const float*)d_in[12];
  const float* W1    = (const float*)d_in[13];
  const float* b1    = (const float*)d_in[14];
  const float* W2    = (const float*)d_in[15];
  const float* b2    = (const float*)d_in[16];
  const float* W3    = (const float*)d_in[17];
  const float* b3    = (const float*)d_in[18];
  const float* Aaff  = (const float*)d_in[19];
  const float* scW1  = (const float*)d_in[20];
  const float* scb1  = (const float*)d_in[21];
  const float* scW2  = (const float*)d_in[22];
  const float* scb2  = (const float*)d_in[23];
  const int*   topk  = (const int*)  d_in[24];

  float* ws    = (float*)d_ws;
  float* feat1 = ws;
  float* feat2 = ws + (size_t)1 * NTF;
  float* f13   = ws + (size_t)2 * NTF;
  float* f23   = ws + (size_t)3 * NTF;
  float* htmp  = ws + (size_t)4 * NTF;
  float* dinv1 = ws + (size_t)5 * NTF;
  float* dinv2 = dinv1 + NT;
  float* gfs   = dinv2 + NT;

  float* ged = (float*)d_out;
  float* S1  = ged + BATCH;
  float* S2  = S1 + (size_t)BATCH * NNODE * NNODE;

  // int scratch lives in S1's output region (only written by affS AFTER chain)
  int* degi1 = (int*)S1;
  int* ofs1  = degi1 + NT;
  int* cur1  = ofs1 + NT;
  int* csr1  = cur1 + NT;
  int* degi2 = csr1 + NEDGE;
  int* ofs2  = degi2 + NT;
  int* cur2  = ofs2 + NT;
  int* csr2  = cur2 + NT;

  const int gMM = NT / 64;   // 512 blocks
  const int gE  = NEDGE / 256;
  const int gN  = NT / 256;

  // CSR + degree norms
  k_zero_i<<<gN, 256, 0, stream>>>(degi1, NT);
  k_zero_i<<<gN, 256, 0, stream>>>(degi2, NT);
  k_deg_count<<<gE, 256, 0, stream>>>(dst1, degi1);
  k_deg_count<<<gE, 256, 0, stream>>>(dst2, degi2);
  k_dinv<<<gN, 256, 0, stream>>>(degi1, dinv1, NT);
  k_dinv<<<gN, 256, 0, stream>>>(degi2, dinv2, NT);
  k_scan<<<1, 1024, 0, stream>>>(degi1, ofs1, cur1);
  k_scan<<<1, 1024, 0, stream>>>(degi2, ofs2, cur2);
  k_csr_fill<<<gE, 256, 0, stream>>>(src1, dst1, cur1, csr1);
  k_csr_fill<<<gE, 256, 0, stream>>>(src2, dst2, cur2, csr2);

  // fused conv chains (both sides), writes feat1/feat2/f13/f23/gfs
  k_chain<<<512, 256, 0, stream>>>(
      x1, cent1, rw1, x2, cent2, rw2, demb, initW, initb,
      W1, b1, W2, b2, W3, b3,
      ofs1, cur1, csr1, ofs2, cur2, csr2, dinv1, dinv2,
      feat1, feat2, f13, f23, gfs);

  // sim1
  k_mm<false><<<gMM, 256, 0, stream>>>(feat1, Aaff, htmp);
  k_affS<<<BATCH * 2, 256, 0, stream>>>(htmp, feat2, S1);
  k_sinkhorn<<<BATCH, 1024, 0, stream>>>(S1, topk);

  // sim2
  k_mm<false><<<gMM, 256, 0, stream>>>(f13, Aaff, htmp);
  k_affS<<<BATCH * 2, 256, 0, stream>>>(htmp, f23, S2);
  k_sinkhorn<<<BATCH, 1024, 0, stream>>>(S2, topk);

  // ged
  k_mlp<<<BATCH, 256, 0, stream>>>(gfs, scW1, scb1, scW2, scb2, ged);
}